// Round 12
// baseline (460.140 us; speedup 1.0000x reference)
//
#include <hip/hip_runtime.h>

#define H 64
#define N_PERSON 200000
#define N_MOVIE 100000
#define E_ACTED 1600000
#define E_DIRECTED 200000
#define E_WWW 3200000
#define E_TOTAL (E_ACTED + E_DIRECTED + E_WWW)

#define SH 11         // bucket = dst >> 11 (2048 dsts per bucket)
#define NBIN 2048
#define CH 16384      // edges per partition block

typedef __attribute__((ext_vector_type(8))) short bf16x8;
typedef __attribute__((ext_vector_type(4))) float f32x4;

static __device__ __forceinline__ ushort f2bf(float f) {
  uint u = __float_as_uint(f);
  uint r = (u + 0x7FFFu + ((u >> 16) & 1u)) >> 16;
  return (ushort)r;
}
static __device__ __forceinline__ float bflo(uint u) { return __uint_as_float(u << 16); }
// high bf16 with low-mantissa garbage (free; rel err <= 2^-7, pull accumulation only)
static __device__ __forceinline__ float bfhiq(uint u) { return __uint_as_float(u); }
static __device__ __forceinline__ uint packbf(float lo, float hi) {
  return (uint)f2bf(lo) | ((uint)f2bf(hi) << 16);
}

// ---------------- relation descriptor ----------------

struct RelP {
  const int* src; const int* dst; int* off;
  int E, N, nblk, nbuk, blkbase, bukbase, cbase, ebase;
};

// ---- fused: per-block coarse histogram (blocks < castbase) + fp32->bf16 cast (rest) ----

static __global__ __launch_bounds__(256) void count_cast_k(RelP a, RelP b, RelP c,
                                                           int* __restrict__ counts, int castbase,
                                                           const float* __restrict__ i0,
                                                           ushort* __restrict__ o0, int n0,
                                                           const float* __restrict__ i1,
                                                           ushort* __restrict__ o1, int n1) {
  int blk = blockIdx.x, t = threadIdx.x;
  if (blk >= castbase) {
    int i = (blk - castbase) * 256 + t;
    int stride = 2048 * 256;
    int nt = n0 + n1;
    for (; i < nt; i += stride) {
      const float4* in; ushort4* out; int idx;
      if (i < n0) { in = (const float4*)i0; out = (ushort4*)o0; idx = i; }
      else { in = (const float4*)i1; out = (ushort4*)o1; idx = i - n0; }
      float4 v = in[idx];
      ushort4 o;
      o.x = f2bf(v.x); o.y = f2bf(v.y); o.z = f2bf(v.z); o.w = f2bf(v.w);
      out[idx] = o;
    }
    return;
  }
  __shared__ int hist[128];
  RelP r = (blk >= c.blkbase) ? c : (blk >= b.blkbase) ? b : a;
  int lb = blk - r.blkbase;
  for (int i = t; i < r.nbuk; i += 256) hist[i] = 0;
  __syncthreads();
  int e0 = lb * CH, e1 = min(e0 + CH, r.E);
  for (int e = e0 + t; e < e1; e += 256) atomicAdd(&hist[r.dst[e] >> SH], 1);
  __syncthreads();
  for (int i = t; i < r.nbuk; i += 256) counts[r.cbase + i * r.nblk + lb] = hist[i];
}

// ---- single-block full exclusive scan (n ~ 25K): chunk-per-thread + wave scan ----

static __global__ __launch_bounds__(1024) void scan_one_k(const int* __restrict__ in, int n,
                                                          int* __restrict__ out, int total) {
  __shared__ int wsum[16];
  int t = threadIdx.x;
  int C = (n + 1023) / 1024;
  int i0 = t * C, i1 = min(i0 + C, n);
  int s = 0;
  for (int i = i0; i < i1; ++i) s += in[i];
  int lane = t & 63, w = t >> 6;
  int incl = s;
  for (int d = 1; d < 64; d <<= 1) {
    int v = __shfl_up(incl, d, 64);
    if (lane >= d) incl += v;
  }
  if (lane == 63) wsum[w] = incl;
  __syncthreads();
  if (t == 0) {
    int acc = 0;
    for (int i = 0; i < 16; ++i) { int v = wsum[i]; wsum[i] = acc; acc += v; }
  }
  __syncthreads();
  int run = wsum[w] + (incl - s);
  for (int i = i0; i < i1; ++i) { int v = in[i]; out[i] = run; run += v; }
  if (t == 0) out[n] = total;
}

// ---------------- partition scatter (packed (dstLow11<<18)|src) ----------------

static __global__ __launch_bounds__(256) void part_scatter_all_k(RelP a, RelP b, RelP c,
                                                                 const int* __restrict__ off_bb,
                                                                 int* __restrict__ pairs) {
  __shared__ int cur[128];
  int blk = blockIdx.x, t = threadIdx.x;
  RelP r = (blk >= c.blkbase) ? c : (blk >= b.blkbase) ? b : a;
  int lb = blk - r.blkbase;
  for (int i = t; i < r.nbuk; i += 256) cur[i] = off_bb[r.cbase + i * r.nblk + lb];
  __syncthreads();
  int e0 = lb * CH, e1 = min(e0 + CH, r.E);
  int e = e0 + t;
  for (; e + 256 < e1; e += 512) {
    int d0 = r.dst[e], s0 = r.src[e];
    int d1 = r.dst[e + 256], s1 = r.src[e + 256];
    int p0 = atomicAdd(&cur[d0 >> SH], 1);
    int p1 = atomicAdd(&cur[d1 >> SH], 1);
    pairs[p0] = ((d0 & (NBIN - 1)) << 18) | s0;  // src < 2^18
    pairs[p1] = ((d1 & (NBIN - 1)) << 18) | s1;
  }
  if (e < e1) {
    int d0 = r.dst[e], s0 = r.src[e];
    int p0 = atomicAdd(&cur[d0 >> SH], 1);
    pairs[p0] = ((d0 & (NBIN - 1)) << 18) | s0;
  }
}

// ---- one block (1024 thr) per coarse bucket: 2048-bin LDS counting sort ----

static __global__ __launch_bounds__(1024) void fine_sort_all_k(RelP a, RelP b, RelP c,
                                                               const int* __restrict__ off_bb,
                                                               const int* __restrict__ pairs,
                                                               int* __restrict__ csr) {
  __shared__ int hist[NBIN];
  __shared__ int wsum[16];
  int bb = blockIdx.x, t = threadIdx.x;
  RelP r = (bb >= c.bukbase) ? c : (bb >= b.bukbase) ? b : a;
  int bkt = bb - r.bukbase;
  int bstart = off_bb[r.cbase + bkt * r.nblk];
  int bend = (bkt + 1 < r.nbuk) ? off_bb[r.cbase + (bkt + 1) * r.nblk] : (r.ebase + r.E);
  int base = bkt << SH;
  int b0 = t * 2, b1 = t * 2 + 1;
  hist[b0] = 0; hist[b1] = 0;
  __syncthreads();
  for (int e = bstart + t; e < bend; e += 1024) atomicAdd(&hist[((uint)pairs[e]) >> 18], 1);
  __syncthreads();
  int h0 = hist[b0], h1 = hist[b1];
  int s = h0 + h1;
  int lane = t & 63, w = t >> 6;
  int incl = s;
  for (int d = 1; d < 64; d <<= 1) {
    int v = __shfl_up(incl, d, 64);
    if (lane >= d) incl += v;
  }
  if (lane == 63) wsum[w] = incl;
  __syncthreads();
  if (t == 0) {
    int acc = 0;
    for (int i = 0; i < 16; ++i) { int v = wsum[i]; wsum[i] = acc; acc += v; }
  }
  __syncthreads();
  int excl = wsum[w] + (incl - s);
  int ex0 = excl, ex1 = excl + h0;
  if (base + b0 < r.N) r.off[base + b0] = bstart + ex0;
  if (base + b1 < r.N) r.off[base + b1] = bstart + ex1;
  if (bkt == r.nbuk - 1 && t == 0) r.off[r.N] = r.ebase + r.E;
  hist[b0] = ex0; hist[b1] = ex1;  // reuse as cursors
  __syncthreads();
  for (int e = bstart + t; e < bend; e += 1024) {
    int p = pairs[e];
    int pos = bstart + atomicAdd(&hist[((uint)p) >> 18], 1);
    csr[pos] = p & 0x3FFFF;
  }
}

// ---- FUSED pull+MFMA GEMM. Per source: either gather-mean into LDS (pull) or global
//      bf16 A. M-tile = 128 (4 waves x 32 rows). C = sum_s A_s @ (W_s [+Wadd])^T + b, relu.
//      Output bf16 or fused 64->1 projection. Two tasks per launch. ----

struct GemmT {
  const ushort *A0, *A1, *A2;        // global A per source (used when offX == nullptr)
  const int *off0, *off1, *off2;     // CSR offsets per source (pull mode when non-null)
  const ushort *gx0, *gx1, *gx2;     // gather tables per source
  const float *W0, *W1, *W2, *Wadd, *b0, *b1;
  ushort* outB;
  const float *projW, *projb;
  float* projOut;
  int M, nsrc, blkbase;
};

#define ACC8(u)                                  \
  do {                                           \
    a0 += bflo((u).x); a1 += bfhiq((u).x);       \
    a2 += bflo((u).y); a3 += bfhiq((u).y);       \
    a4 += bflo((u).z); a5 += bfhiq((u).z);       \
    a6 += bflo((u).w); a7 += bfhiq((u).w);       \
  } while (0)

#define GATHER1(ii)                                        \
  do {                                                     \
    int s_ = csr[e0 + (ii)];                               \
    uint4 u_ = *(const uint4*)(xrow + (size_t)s_ * 64);    \
    ACC8(u_);                                              \
  } while (0)

static __global__ __launch_bounds__(256) void gemm_all_k(GemmT g0, GemmT g1,
                                                         const int* __restrict__ csr) {
  GemmT g = (g1.M > 0 && (int)blockIdx.x >= g1.blkbase) ? g1 : g0;
  __shared__ ushort Wt[3][64][72];  // 27.6 KB
  __shared__ ushort Mb[128][72];    // 18 KB pulled-mean tile (stride 144B: 2-way banks)
  const int t = threadIdx.x;
  const int w = t >> 6;   // wave: rows [w*32, w*32+32)
  const int l = t & 63;
  const int lr = l & 15;
  const int lk = l >> 4;
  const int gg = l >> 3;  // pull: dst slot in octet
  const int fo = l & 7;   // pull: feature octet
  const int m0 = ((int)blockIdx.x - g.blkbase) * 128;

  const ushort* As[3] = {g.A0, g.A1, g.A2};
  const int* offs[3] = {g.off0, g.off1, g.off2};
  const ushort* gxs[3] = {g.gx0, g.gx1, g.gx2};
  const float* Ws[3] = {g.W0, g.W1, g.W2};

  auto stageW = [&](const float* W, int s, const float* Wa) {
#pragma unroll
    for (int i = 0; i < 8; ++i) {
      int dp = t + i * 256;
      int j = dp >> 5;
      int kk = (dp & 31) * 2;
      float2 wv = *(const float2*)(W + j * 64 + kk);
      if (Wa) {
        float2 av = *(const float2*)(Wa + j * 64 + kk);
        wv.x += av.x; wv.y += av.y;
      }
      *(uint*)&Wt[s][j][kk] = packbf(wv.x, wv.y);
    }
  };
  stageW(g.W0, 0, nullptr);
  stageW(g.W1, 1, g.nsrc == 2 ? g.Wadd : nullptr);
  if (g.nsrc > 2) stageW(g.W2, 2, g.Wadd);

  f32x4 acc[2][4];
#pragma unroll
  for (int mt = 0; mt < 2; ++mt)
#pragma unroll
    for (int jt = 0; jt < 4; ++jt) acc[mt][jt] = (f32x4){0.f, 0.f, 0.f, 0.f};

  for (int s = 0; s < g.nsrc; ++s) {
    bf16x8 aF[2][2];
    if (offs[s]) {
      __syncthreads();  // protect Mb reuse (and cover W staging on first source)
      const int* off = offs[s];
      const ushort* __restrict__ xrow = gxs[s] + fo * 8;
      for (int rr = 0; rr < 4; ++rr) {
        int dl = w * 32 + rr * 8 + gg;
        int d = m0 + dl;
        bool dok = d < g.M;
        int dd = dok ? d : (g.M - 1);
        int e0 = off[dd];
        int e1 = off[dd + 1];
        int cnt = dok ? (e1 - e0) : 0;
        int mx = cnt;
        mx = max(mx, __shfl_xor(mx, 8, 64));
        mx = max(mx, __shfl_xor(mx, 16, 64));
        mx = max(mx, __shfl_xor(mx, 32, 64));
        float a0 = 0.f, a1 = 0.f, a2 = 0.f, a3 = 0.f, a4 = 0.f, a5 = 0.f, a6 = 0.f, a7 = 0.f;
        int i = 0;
        for (; i + 4 <= mx; i += 4) {
          if (i + 4 <= cnt) {  // 4 gathers in flight (restores miss depth at low occupancy)
            int s0 = csr[e0 + i], s1 = csr[e0 + i + 1];
            int s2 = csr[e0 + i + 2], s3 = csr[e0 + i + 3];
            uint4 u0 = *(const uint4*)(xrow + (size_t)s0 * 64);
            uint4 u1 = *(const uint4*)(xrow + (size_t)s1 * 64);
            uint4 u2 = *(const uint4*)(xrow + (size_t)s2 * 64);
            uint4 u3 = *(const uint4*)(xrow + (size_t)s3 * 64);
            ACC8(u0); ACC8(u1); ACC8(u2); ACC8(u3);
          } else if (i < cnt) {
#pragma unroll
            for (int k = 0; k < 3; ++k)
              if (i + k < cnt) GATHER1(i + k);
          }
        }
        for (; i < mx; ++i)
          if (i < cnt) GATHER1(i);
        float inv = 1.0f / fmaxf((float)cnt, 1.0f);
        uint4 o;
        o.x = packbf(a0 * inv, a1 * inv);
        o.y = packbf(a2 * inv, a3 * inv);
        o.z = packbf(a4 * inv, a5 * inv);
        o.w = packbf(a6 * inv, a7 * inv);
        *(uint4*)&Mb[dl][fo * 8] = o;
      }
      __syncthreads();
#pragma unroll
      for (int mt = 0; mt < 2; ++mt) {
        int row = w * 32 + mt * 16 + lr;
        aF[mt][0] = *(const bf16x8*)&Mb[row][lk * 8];
        aF[mt][1] = *(const bf16x8*)&Mb[row][32 + lk * 8];
      }
    } else {
      if (s == 0) __syncthreads();  // ensure W staged if no pull preceded
      const ushort* A = As[s];
#pragma unroll
      for (int mt = 0; mt < 2; ++mt) {
        int m = m0 + w * 32 + mt * 16 + lr;
        const ushort* ap = A + (size_t)(m < g.M ? m : 0) * 64 + lk * 8;
        aF[mt][0] = *(const bf16x8*)(ap);
        aF[mt][1] = *(const bf16x8*)(ap + 32);
      }
    }
#pragma unroll
    for (int jt = 0; jt < 4; ++jt) {
#pragma unroll
      for (int k0 = 0; k0 < 2; ++k0) {
        bf16x8 bF = *(const bf16x8*)&Wt[s][jt * 16 + lr][k0 * 32 + lk * 8];
#pragma unroll
        for (int mt = 0; mt < 2; ++mt)
          acc[mt][jt] =
              __builtin_amdgcn_mfma_f32_16x16x32_bf16(bF, aF[mt][k0], acc[mt][jt], 0, 0, 0);
      }
    }
  }

  f32x4 bv[4];
#pragma unroll
  for (int jt = 0; jt < 4; ++jt) {
    f32x4 b = (f32x4){0.f, 0.f, 0.f, 0.f};
    if (g.b0) b += *(const f32x4*)(g.b0 + jt * 16 + lk * 4);
    if (g.b1) b += *(const f32x4*)(g.b1 + jt * 16 + lk * 4);
    bv[jt] = b;
  }

  if (g.projOut) {
    f32x4 pw[4];
#pragma unroll
    for (int jt = 0; jt < 4; ++jt) pw[jt] = *(const f32x4*)(g.projW + jt * 16 + lk * 4);
    float pb = g.projb[0];
#pragma unroll
    for (int mt = 0; mt < 2; ++mt) {
      float p = 0.f;
#pragma unroll
      for (int jt = 0; jt < 4; ++jt) {
        f32x4 o = acc[mt][jt] + bv[jt];
#pragma unroll
        for (int q = 0; q < 4; ++q) p += fmaxf(o[q], 0.f) * pw[jt][q];
      }
      p += __shfl_xor(p, 16, 64);
      p += __shfl_xor(p, 32, 64);
      int m = m0 + w * 32 + mt * 16 + lr;
      if (lk == 0 && m < g.M) g.projOut[m] = p + pb;
    }
  } else {
#pragma unroll
    for (int mt = 0; mt < 2; ++mt) {
      int m = m0 + w * 32 + mt * 16 + lr;
      if (m < g.M) {
        ushort* row = g.outB + (size_t)m * 64 + lk * 4;
#pragma unroll
        for (int jt = 0; jt < 4; ++jt) {
          f32x4 o = acc[mt][jt] + bv[jt];
          uint2 pk;
          pk.x = packbf(fmaxf(o[0], 0.f), fmaxf(o[1], 0.f));
          pk.y = packbf(fmaxf(o[2], 0.f), fmaxf(o[3], 0.f));
          *(uint2*)(row + jt * 16) = pk;
        }
      }
    }
  }
}

// ---------------- launch ----------------

extern "C" void kernel_launch(void* const* d_in, const int* in_sizes, int n_in, void* d_out,
                              int out_size, void* d_ws, size_t ws_size, hipStream_t stream) {
  const float* x_person = (const float*)d_in[0];
  const float* x_movie = (const float*)d_in[1];
  const int* acted_src = (const int*)d_in[2];
  const int* acted_dst = (const int*)d_in[3];
  const int* directed_src = (const int*)d_in[4];
  const int* directed_dst = (const int*)d_in[5];
  const int* www_src = (const int*)d_in[6];
  const int* www_dst = (const int*)d_in[7];
  const float* Wl_acted = (const float*)d_in[8];
  const float* bl_acted = (const float*)d_in[9];
  const float* Wr_acted = (const float*)d_in[10];
  const float* Wl_directed = (const float*)d_in[11];
  const float* bl_directed = (const float*)d_in[12];
  const float* Wr_directed = (const float*)d_in[13];
  const float* Wl_www = (const float*)d_in[14];
  const float* bl_www = (const float*)d_in[15];
  const float* Wr_www = (const float*)d_in[16];
  const float* lin_W = (const float*)d_in[17];
  const float* lin_b = (const float*)d_in[18];
  float* out = (float*)d_out;
  (void)in_sizes; (void)n_in; (void)out_size; (void)ws_size;

  char* base = (char*)d_ws;
  size_t pos = 0;
  auto carve = [&](size_t b) -> void* {
    void* r = base + pos;
    pos += (b + 255) & ~(size_t)255;
    return r;
  };
  int* off_a = (int*)carve((N_MOVIE + 1) * sizeof(int));
  int* off_d = (int*)carve((N_MOVIE + 1) * sizeof(int));
  int* off_w = (int*)carve((N_PERSON + 1) * sizeof(int));
  int* csr_all = (int*)carve((size_t)E_TOTAL * sizeof(int));
  int* pairs = (int*)carve((size_t)E_TOTAL * sizeof(int));
  ushort* xpbf = (ushort*)carve((size_t)N_PERSON * H * sizeof(ushort));
  ushort* xmbf = (ushort*)carve((size_t)N_MOVIE * H * sizeof(ushort));
  ushort* xp0bf = (ushort*)carve((size_t)N_PERSON * H * sizeof(ushort));
  ushort* xm0bf = (ushort*)carve((size_t)N_MOVIE * H * sizeof(ushort));

  // relation descriptors (A=acted, D=directed, W=www), contiguous in counts/edges
  RelP rA, rD, rW;
  rA.src = acted_src;  rA.dst = acted_dst;  rA.off = off_a;
  rA.E = E_ACTED;      rA.N = N_MOVIE;
  rA.nblk = (E_ACTED + CH - 1) / CH;      rA.nbuk = (N_MOVIE + NBIN - 1) >> SH;
  rD.src = directed_src; rD.dst = directed_dst; rD.off = off_d;
  rD.E = E_DIRECTED;     rD.N = N_MOVIE;
  rD.nblk = (E_DIRECTED + CH - 1) / CH;   rD.nbuk = (N_MOVIE + NBIN - 1) >> SH;
  rW.src = www_src;    rW.dst = www_dst;  rW.off = off_w;
  rW.E = E_WWW;        rW.N = N_PERSON;
  rW.nblk = (E_WWW + CH - 1) / CH;        rW.nbuk = (N_PERSON + NBIN - 1) >> SH;
  rA.blkbase = 0;                 rD.blkbase = rA.nblk;           rW.blkbase = rA.nblk + rD.nblk;
  rA.bukbase = 0;                 rD.bukbase = rA.nbuk;           rW.bukbase = rA.nbuk + rD.nbuk;
  rA.cbase = 0;                   rD.cbase = rA.nbuk * rA.nblk;
  rW.cbase = rD.cbase + rD.nbuk * rD.nblk;
  rA.ebase = 0;                   rD.ebase = E_ACTED;             rW.ebase = E_ACTED + E_DIRECTED;
  const int n_total = rW.cbase + rW.nbuk * rW.nblk;
  const int nblk_total = rW.blkbase + rW.nblk;
  const int nbuk_total = rW.bukbase + rW.nbuk;

  int* counts = (int*)carve((size_t)n_total * sizeof(int));
  int* off_bb = (int*)carve((size_t)(n_total + 1) * sizeof(int));

  // ---- CSR build + casts ----
  count_cast_k<<<nblk_total + 2048, 256, 0, stream>>>(rA, rD, rW, counts, nblk_total, x_person,
                                                      xpbf, N_PERSON * H / 4, x_movie, xmbf,
                                                      N_MOVIE * H / 4);
  scan_one_k<<<1, 1024, 0, stream>>>(counts, n_total, off_bb, E_TOTAL);
  part_scatter_all_k<<<nblk_total, 256, 0, stream>>>(rA, rD, rW, off_bb, pairs);
  fine_sort_all_k<<<nbuk_total, 1024, 0, stream>>>(rA, rD, rW, off_bb, pairs, csr_all);

  const int gmM = (N_MOVIE + 127) / 128, gmP = (N_PERSON + 127) / 128;

  // ---- layer 1: movie {pullA, pullD, xmbf} + person {pullW, xpbf}, one launch ----
  {
    GemmT gM{};
    gM.A2 = xmbf;
    gM.off0 = off_a; gM.gx0 = xpbf;
    gM.off1 = off_d; gM.gx1 = xpbf;
    gM.W0 = Wl_acted; gM.W1 = Wl_directed; gM.W2 = Wr_acted; gM.Wadd = Wr_directed;
    gM.b0 = bl_acted; gM.b1 = bl_directed;
    gM.outB = xm0bf;
    gM.M = N_MOVIE; gM.nsrc = 3; gM.blkbase = 0;
    GemmT gP{};
    gP.A1 = xpbf;
    gP.off0 = off_w; gP.gx0 = xpbf;
    gP.W0 = Wl_www; gP.W1 = Wr_www;
    gP.b0 = bl_www;
    gP.outB = xp0bf;
    gP.M = N_PERSON; gP.nsrc = 2; gP.blkbase = gmM;
    gemm_all_k<<<gmM + gmP, 256, 0, stream>>>(gM, gP, csr_all);
  }
  // ---- layer 2: movie {pullA(xp0bf), pullD(xp0bf), xm0bf} + fused projection ----
  {
    GemmT gM{};
    gM.A2 = xm0bf;
    gM.off0 = off_a; gM.gx0 = xp0bf;
    gM.off1 = off_d; gM.gx1 = xp0bf;
    gM.W0 = Wl_acted + 4096; gM.W1 = Wl_directed + 4096;
    gM.W2 = Wr_acted + 4096; gM.Wadd = Wr_directed + 4096;
    gM.b0 = bl_acted + 64; gM.b1 = bl_directed + 64;
    gM.projW = lin_W; gM.projb = lin_b; gM.projOut = out;
    gM.M = N_MOVIE; gM.nsrc = 3; gM.blkbase = 0;
    GemmT gZ{};
    gemm_all_k<<<gmM, 256, 0, stream>>>(gM, gZ, csr_all);
  }
}

// Round 13
// 340.216 us; speedup vs baseline: 1.3525x; 1.3525x over previous
//
#include <hip/hip_runtime.h>

#define H 64
#define N_PERSON 200000
#define N_MOVIE 100000
#define E_ACTED 1600000
#define E_DIRECTED 200000
#define E_WWW 3200000
#define E_TOTAL (E_ACTED + E_DIRECTED + E_WWW)

#define SH 11         // bucket = dst >> 11 (2048 dsts per bucket)
#define NBIN 2048
#define CH 16384      // edges per partition block

typedef __attribute__((ext_vector_type(8))) short bf16x8;
typedef __attribute__((ext_vector_type(4))) float f32x4;

static __device__ __forceinline__ ushort f2bf(float f) {
  uint u = __float_as_uint(f);
  uint r = (u + 0x7FFFu + ((u >> 16) & 1u)) >> 16;
  return (ushort)r;
}
static __device__ __forceinline__ float bflo(uint u) { return __uint_as_float(u << 16); }
static __device__ __forceinline__ float bfhi(uint u) { return __uint_as_float(u & 0xFFFF0000u); }
// high bf16 with low-mantissa garbage (free; rel err <= 2^-7, used in pull accumulation only)
static __device__ __forceinline__ float bfhiq(uint u) { return __uint_as_float(u); }
static __device__ __forceinline__ uint packbf(float lo, float hi) {
  return (uint)f2bf(lo) | ((uint)f2bf(hi) << 16);
}

// ---------------- relation descriptor ----------------

struct RelP {
  const int* src; const int* dst; int* off;
  int E, N, nblk, nbuk, blkbase, bukbase, cbase, ebase;
};

// ---------------- fp32 -> bf16 cast (two tensors, one launch) ----------------

static __global__ __launch_bounds__(256) void cast_all_k(const float* __restrict__ i0,
                                                         ushort* __restrict__ o0, int n0,
                                                         const float* __restrict__ i1,
                                                         ushort* __restrict__ o1, int n1) {
  int i = blockIdx.x * 256 + threadIdx.x;
  int stride = gridDim.x * 256;
  int nt = n0 + n1;
  for (; i < nt; i += stride) {
    const float4* in; ushort4* out; int idx;
    if (i < n0) { in = (const float4*)i0; out = (ushort4*)o0; idx = i; }
    else { in = (const float4*)i1; out = (ushort4*)o1; idx = i - n0; }
    float4 v = in[idx];
    ushort4 o;
    o.x = f2bf(v.x); o.y = f2bf(v.y); o.z = f2bf(v.z); o.w = f2bf(v.w);
    out[idx] = o;
  }
}

// ---------------- scan helpers ----------------

static __global__ __launch_bounds__(1024) void scan_block_k(const int* __restrict__ in, int n,
                                                            int* __restrict__ out,
                                                            int* __restrict__ partials) {
  __shared__ int sm[1024];
  int tid = threadIdx.x;
  int gid = blockIdx.x * 1024 + tid;
  int v = (gid < n) ? in[gid] : 0;
  sm[tid] = v;
  __syncthreads();
  for (int d = 1; d < 1024; d <<= 1) {
    int t = (tid >= d) ? sm[tid - d] : 0;
    __syncthreads();
    if (tid >= d) sm[tid] += t;
    __syncthreads();
  }
  if (gid < n) out[gid] = sm[tid] - v;  // exclusive
  if (tid == 1023 && partials) partials[blockIdx.x] = sm[1023];
}

static __global__ __launch_bounds__(1024) void add_off_k(int* __restrict__ off, int n,
                                                         const int* __restrict__ parts, int total) {
  int gid = blockIdx.x * 1024 + threadIdx.x;
  if (gid < n) off[gid] += parts[gid >> 10];
  else if (gid == n) off[gid] = total;
}

// ---------------- two-level counting sort, all relations fused ----------------

static __global__ __launch_bounds__(256) void part_count_all_k(RelP a, RelP b, RelP c,
                                                               int* __restrict__ counts) {
  __shared__ int hist[128];
  int blk = blockIdx.x, t = threadIdx.x;
  RelP r = (blk >= c.blkbase) ? c : (blk >= b.blkbase) ? b : a;
  int lb = blk - r.blkbase;
  for (int i = t; i < r.nbuk; i += 256) hist[i] = 0;
  __syncthreads();
  int e0 = lb * CH, e1 = min(e0 + CH, r.E);
  for (int e = e0 + t; e < e1; e += 256) atomicAdd(&hist[r.dst[e] >> SH], 1);
  __syncthreads();
  for (int i = t; i < r.nbuk; i += 256) counts[r.cbase + i * r.nblk + lb] = hist[i];
}

static __global__ __launch_bounds__(256) void part_scatter_all_k(RelP a, RelP b, RelP c,
                                                                 const int* __restrict__ off_bb,
                                                                 int* __restrict__ pairs) {
  __shared__ int cur[128];
  int blk = blockIdx.x, t = threadIdx.x;
  RelP r = (blk >= c.blkbase) ? c : (blk >= b.blkbase) ? b : a;
  int lb = blk - r.blkbase;
  for (int i = t; i < r.nbuk; i += 256) cur[i] = off_bb[r.cbase + i * r.nblk + lb];
  __syncthreads();
  int e0 = lb * CH, e1 = min(e0 + CH, r.E);
  int e = e0 + t;
  for (; e + 256 < e1; e += 512) {
    int d0 = r.dst[e], s0 = r.src[e];
    int d1 = r.dst[e + 256], s1 = r.src[e + 256];
    int p0 = atomicAdd(&cur[d0 >> SH], 1);
    int p1 = atomicAdd(&cur[d1 >> SH], 1);
    pairs[p0] = ((d0 & (NBIN - 1)) << 18) | s0;  // src < 2^18
    pairs[p1] = ((d1 & (NBIN - 1)) << 18) | s1;
  }
  if (e < e1) {
    int d0 = r.dst[e], s0 = r.src[e];
    int p0 = atomicAdd(&cur[d0 >> SH], 1);
    pairs[p0] = ((d0 & (NBIN - 1)) << 18) | s0;
  }
}

// one block (1024 thr) per coarse bucket: 2048-bin LDS counting sort
static __global__ __launch_bounds__(1024) void fine_sort_all_k(RelP a, RelP b, RelP c,
                                                               const int* __restrict__ off_bb,
                                                               const int* __restrict__ pairs,
                                                               int* __restrict__ csr) {
  __shared__ int hist[NBIN];
  __shared__ int sc[NBIN];
  int bb = blockIdx.x, t = threadIdx.x;
  RelP r = (bb >= c.bukbase) ? c : (bb >= b.bukbase) ? b : a;
  int bkt = bb - r.bukbase;
  int bstart = off_bb[r.cbase + bkt * r.nblk];
  int bend = (bkt + 1 < r.nbuk) ? off_bb[r.cbase + (bkt + 1) * r.nblk] : (r.ebase + r.E);
  int base = bkt << SH;
  hist[t] = 0; hist[t + 1024] = 0;
  __syncthreads();
  for (int e = bstart + t; e < bend; e += 1024) atomicAdd(&hist[((uint)pairs[e]) >> 18], 1);
  __syncthreads();
  sc[t] = hist[t]; sc[t + 1024] = hist[t + 1024];
  __syncthreads();
  for (int d = 1; d < NBIN; d <<= 1) {
    int v0 = (t >= d) ? sc[t - d] : 0;
    int v1 = (t + 1024 >= d) ? sc[t + 1024 - d] : 0;
    __syncthreads();
    sc[t] += v0; sc[t + 1024] += v1;
    __syncthreads();
  }
  int ex0 = sc[t] - hist[t];
  int ex1 = sc[t + 1024] - hist[t + 1024];
  if (base + t < r.N) r.off[base + t] = bstart + ex0;
  if (base + t + 1024 < r.N) r.off[base + t + 1024] = bstart + ex1;
  if (bkt == r.nbuk - 1 && t == 0) r.off[r.N] = r.ebase + r.E;
  hist[t] = ex0; hist[t + 1024] = ex1;  // reuse as cursors
  __syncthreads();
  for (int e = bstart + t; e < bend; e += 1024) {
    int p = pairs[e];
    int pos = bstart + atomicAdd(&hist[((uint)p) >> 18], 1);
    csr[pos] = p & 0x3FFFF;
  }
}

// ---------------- multi-task pull mean (bf16 in, bf16 out) ----------------
// 8 dsts per wave: lane = (g = lane>>3 dst slot, fo = lane&7 feature octet).
// 2 gathers in flight; high occupancy (16 VGPR, no LDS) is what sustains the
// random-gather concurrency — r8 (depth-4 null), r10 (fp8 regression), r12
// (GEMM-fusion at 28% occupancy -> BW halved) all confirm this structure is
// at the pattern floor: ~285 MB TCC-fetch @ ~3.3 TB/s.

struct PullT { const ushort* xsrc; const int* off; ushort* mean; int n; int blkbase; };

#define ACC8(u)                                  \
  do {                                           \
    a0 += bflo((u).x); a1 += bfhiq((u).x);       \
    a2 += bflo((u).y); a3 += bfhiq((u).y);       \
    a4 += bflo((u).z); a5 += bfhiq((u).z);       \
    a6 += bflo((u).w); a7 += bfhiq((u).w);       \
  } while (0)

static __global__ __launch_bounds__(256) void pull_all_k(PullT t0, PullT t1, PullT t2,
                                                         const int* __restrict__ csr) {
  int blk = blockIdx.x;
  PullT tk;
  if (t2.n > 0 && blk >= t2.blkbase) tk = t2;
  else if (blk >= t1.blkbase) tk = t1;
  else tk = t0;
  int lane = threadIdx.x & 63;
  int g = lane >> 3;   // dst slot within wave
  int fo = lane & 7;   // feature octet
  int d = ((blk - tk.blkbase) * 4 + (threadIdx.x >> 6)) * 8 + g;
  bool dok = d < tk.n;
  int dd = dok ? d : (tk.n - 1);
  int e0 = tk.off[dd];
  int e1 = tk.off[dd + 1];
  int cnt = dok ? (e1 - e0) : 0;
  int mx = cnt;
  mx = max(mx, __shfl_xor(mx, 8, 64));
  mx = max(mx, __shfl_xor(mx, 16, 64));
  mx = max(mx, __shfl_xor(mx, 32, 64));

  const ushort* __restrict__ xrow = tk.xsrc + fo * 8;
  float a0 = 0.f, a1 = 0.f, a2 = 0.f, a3 = 0.f, a4 = 0.f, a5 = 0.f, a6 = 0.f, a7 = 0.f;

  int i = 0;
  for (; i + 2 <= mx; i += 2) {
    if (i + 1 < cnt) {
      int s0 = csr[e0 + i];
      int s1 = csr[e0 + i + 1];
      uint4 u0 = *(const uint4*)(xrow + (size_t)s0 * 64);
      uint4 u1 = *(const uint4*)(xrow + (size_t)s1 * 64);
      ACC8(u0); ACC8(u1);
    } else if (i < cnt) {
      int s0 = csr[e0 + i];
      uint4 u0 = *(const uint4*)(xrow + (size_t)s0 * 64);
      ACC8(u0);
    }
  }
  if (i < mx && i < cnt) {
    int s0 = csr[e0 + i];
    uint4 u0 = *(const uint4*)(xrow + (size_t)s0 * 64);
    ACC8(u0);
  }

  if (dok) {
    float inv = 1.0f / fmaxf((float)cnt, 1.0f);
    uint4 o;
    o.x = packbf(a0 * inv, a1 * inv);
    o.y = packbf(a2 * inv, a3 * inv);
    o.z = packbf(a4 * inv, a5 * inv);
    o.w = packbf(a6 * inv, a7 * inv);
    *(uint4*)(tk.mean + (size_t)d * 64 + fo * 8) = o;
  }
}

// ---- MFMA GEMM (bf16 A, bf16 W, fp32 acc): C = sum_s A_s @ (W_s [+Wadd])^T + b0 + b1, relu;
//      output bf16, or fused 64->1 projection. Two tasks per launch.
//      256 rows/block, 4 waves x 4 m-tiles x 4 j-tiles, mfma_f32_16x16x32_bf16 with
//      SWAPPED operands (D[j][m]) so each lane owns 4 consecutive cols of one C row. ----

struct GemmT {
  const ushort *A0, *A1, *A2;
  const float *W0, *W1, *W2, *Wadd, *b0, *b1;
  ushort* outB;
  const float *projW, *projb;
  float* projOut;
  int M, nsrc, blkbase;
};

static __global__ __launch_bounds__(256) void gemm_all_k(GemmT g0, GemmT g1) {
  GemmT g = (g1.M > 0 && (int)blockIdx.x >= g1.blkbase) ? g1 : g0;
  __shared__ ushort Wt[3][64][72];  // bf16, padded stride 72 (conflict-light b128 reads)
  const int t = threadIdx.x;
  const int w = t >> 6;   // wave: rows [w*64, w*64+64) of the block tile
  const int l = t & 63;
  const int lr = l & 15;  // fragment row selector / C-col(m) selector in D'
  const int lk = l >> 4;  // k-octet selector / j-quad selector in D'
  const int m0 = ((int)blockIdx.x - g.blkbase) * 256;

  // ---- stage W (+Wadd on last src) into LDS as bf16 ----
  auto stageW = [&](const float* W, int s, const float* Wa) {
#pragma unroll
    for (int i = 0; i < 8; ++i) {
      int dp = t + i * 256;      // dword-pair index 0..2047
      int j = dp >> 5;           // row 0..63
      int kk = (dp & 31) * 2;    // k 0..62 even
      float2 wv = *(const float2*)(W + j * 64 + kk);
      if (Wa) {
        float2 av = *(const float2*)(Wa + j * 64 + kk);
        wv.x += av.x; wv.y += av.y;
      }
      *(uint*)&Wt[s][j][kk] = packbf(wv.x, wv.y);
    }
  };
  stageW(g.W0, 0, nullptr);
  stageW(g.W1, 1, g.nsrc == 2 ? g.Wadd : nullptr);
  if (g.nsrc > 2) stageW(g.W2, 2, g.Wadd);
  __syncthreads();

  f32x4 acc[4][4];  // [mt][jt]; lane holds C[m0+w*64+mt*16+lr][jt*16+lk*4+q]
#pragma unroll
  for (int mt = 0; mt < 4; ++mt)
#pragma unroll
    for (int jt = 0; jt < 4; ++jt) acc[mt][jt] = (f32x4){0.f, 0.f, 0.f, 0.f};

  auto doSrc = [&](const ushort* A, int s) {
    bf16x8 aF[4][2];
#pragma unroll
    for (int mt = 0; mt < 4; ++mt) {
      int m = m0 + w * 64 + mt * 16 + lr;
      const ushort* ap = A + (size_t)(m < g.M ? m : 0) * 64 + lk * 8;
      aF[mt][0] = *(const bf16x8*)(ap);
      aF[mt][1] = *(const bf16x8*)(ap + 32);
    }
#pragma unroll
    for (int jt = 0; jt < 4; ++jt) {
#pragma unroll
      for (int k0 = 0; k0 < 2; ++k0) {
        bf16x8 bF = *(const bf16x8*)&Wt[s][jt * 16 + lr][k0 * 32 + lk * 8];
#pragma unroll
        for (int mt = 0; mt < 4; ++mt)
          acc[mt][jt] =
              __builtin_amdgcn_mfma_f32_16x16x32_bf16(bF, aF[mt][k0], acc[mt][jt], 0, 0, 0);
      }
    }
  };
  doSrc(g.A0, 0);
  doSrc(g.A1, 1);
  if (g.nsrc > 2) doSrc(g.A2, 2);

  f32x4 bv[4];
#pragma unroll
  for (int jt = 0; jt < 4; ++jt) {
    f32x4 b = (f32x4){0.f, 0.f, 0.f, 0.f};
    if (g.b0) b += *(const f32x4*)(g.b0 + jt * 16 + lk * 4);
    if (g.b1) b += *(const f32x4*)(g.b1 + jt * 16 + lk * 4);
    bv[jt] = b;
  }

  if (g.projOut) {
    f32x4 pw[4];
#pragma unroll
    for (int jt = 0; jt < 4; ++jt) pw[jt] = *(const f32x4*)(g.projW + jt * 16 + lk * 4);
    float pb = g.projb[0];
#pragma unroll
    for (int mt = 0; mt < 4; ++mt) {
      float p = 0.f;
#pragma unroll
      for (int jt = 0; jt < 4; ++jt) {
        f32x4 o = acc[mt][jt] + bv[jt];
#pragma unroll
        for (int q = 0; q < 4; ++q) p += fmaxf(o[q], 0.f) * pw[jt][q];
      }
      p += __shfl_xor(p, 16, 64);
      p += __shfl_xor(p, 32, 64);
      int m = m0 + w * 64 + mt * 16 + lr;
      if (lk == 0 && m < g.M) g.projOut[m] = p + pb;
    }
  } else {
#pragma unroll
    for (int mt = 0; mt < 4; ++mt) {
      int m = m0 + w * 64 + mt * 16 + lr;
      if (m < g.M) {
        ushort* row = g.outB + (size_t)m * 64 + lk * 4;
#pragma unroll
        for (int jt = 0; jt < 4; ++jt) {
          f32x4 o = acc[mt][jt] + bv[jt];
          uint2 pk;
          pk.x = packbf(fmaxf(o[0], 0.f), fmaxf(o[1], 0.f));
          pk.y = packbf(fmaxf(o[2], 0.f), fmaxf(o[3], 0.f));
          *(uint2*)(row + jt * 16) = pk;
        }
      }
    }
  }
}

// ---------------- launch ----------------

extern "C" void kernel_launch(void* const* d_in, const int* in_sizes, int n_in, void* d_out,
                              int out_size, void* d_ws, size_t ws_size, hipStream_t stream) {
  const float* x_person = (const float*)d_in[0];
  const float* x_movie = (const float*)d_in[1];
  const int* acted_src = (const int*)d_in[2];
  const int* acted_dst = (const int*)d_in[3];
  const int* directed_src = (const int*)d_in[4];
  const int* directed_dst = (const int*)d_in[5];
  const int* www_src = (const int*)d_in[6];
  const int* www_dst = (const int*)d_in[7];
  const float* Wl_acted = (const float*)d_in[8];
  const float* bl_acted = (const float*)d_in[9];
  const float* Wr_acted = (const float*)d_in[10];
  const float* Wl_directed = (const float*)d_in[11];
  const float* bl_directed = (const float*)d_in[12];
  const float* Wr_directed = (const float*)d_in[13];
  const float* Wl_www = (const float*)d_in[14];
  const float* bl_www = (const float*)d_in[15];
  const float* Wr_www = (const float*)d_in[16];
  const float* lin_W = (const float*)d_in[17];
  const float* lin_b = (const float*)d_in[18];
  float* out = (float*)d_out;
  (void)in_sizes; (void)n_in; (void)out_size; (void)ws_size;

  char* base = (char*)d_ws;
  size_t pos = 0;
  auto carve = [&](size_t b) -> void* {
    void* r = base + pos;
    pos += (b + 255) & ~(size_t)255;
    return r;
  };
  int* off_a = (int*)carve((N_MOVIE + 1) * sizeof(int));
  int* off_d = (int*)carve((N_MOVIE + 1) * sizeof(int));
  int* off_w = (int*)carve((N_PERSON + 1) * sizeof(int));
  int* parts = (int*)carve(1024 * sizeof(int));
  int* csr_all = (int*)carve((size_t)E_TOTAL * sizeof(int));
  int* pairs = (int*)carve((size_t)E_TOTAL * sizeof(int));
  ushort* xpbf = (ushort*)carve((size_t)N_PERSON * H * sizeof(ushort));
  ushort* xmbf = (ushort*)carve((size_t)N_MOVIE * H * sizeof(ushort));
  ushort* xp0bf = (ushort*)carve((size_t)N_PERSON * H * sizeof(ushort));
  ushort* xm0bf = (ushort*)carve((size_t)N_MOVIE * H * sizeof(ushort));
  ushort* meanAbf = (ushort*)carve((size_t)N_MOVIE * H * sizeof(ushort));
  ushort* meanDbf = (ushort*)carve((size_t)N_MOVIE * H * sizeof(ushort));
  ushort* meanWbf = (ushort*)carve((size_t)N_PERSON * H * sizeof(ushort));

  // relation descriptors (A=acted, D=directed, W=www), contiguous in counts/edges
  RelP rA, rD, rW;
  rA.src = acted_src;  rA.dst = acted_dst;  rA.off = off_a;
  rA.E = E_ACTED;      rA.N = N_MOVIE;
  rA.nblk = (E_ACTED + CH - 1) / CH;      rA.nbuk = (N_MOVIE + NBIN - 1) >> SH;
  rD.src = directed_src; rD.dst = directed_dst; rD.off = off_d;
  rD.E = E_DIRECTED;     rD.N = N_MOVIE;
  rD.nblk = (E_DIRECTED + CH - 1) / CH;   rD.nbuk = (N_MOVIE + NBIN - 1) >> SH;
  rW.src = www_src;    rW.dst = www_dst;  rW.off = off_w;
  rW.E = E_WWW;        rW.N = N_PERSON;
  rW.nblk = (E_WWW + CH - 1) / CH;        rW.nbuk = (N_PERSON + NBIN - 1) >> SH;
  rA.blkbase = 0;                 rD.blkbase = rA.nblk;           rW.blkbase = rA.nblk + rD.nblk;
  rA.bukbase = 0;                 rD.bukbase = rA.nbuk;           rW.bukbase = rA.nbuk + rD.nbuk;
  rA.cbase = 0;                   rD.cbase = rA.nbuk * rA.nblk;
  rW.cbase = rD.cbase + rD.nbuk * rD.nblk;
  rA.ebase = 0;                   rD.ebase = E_ACTED;             rW.ebase = E_ACTED + E_DIRECTED;
  const int n_total = rW.cbase + rW.nbuk * rW.nblk;
  const int nblk_total = rW.blkbase + rW.nblk;
  const int nbuk_total = rW.bukbase + rW.nbuk;

  int* counts = (int*)carve((size_t)n_total * sizeof(int));
  int* off_bb = (int*)carve((size_t)(n_total + 1) * sizeof(int));

  // ---- CSR build (all relations in each launch) ----
  part_count_all_k<<<nblk_total, 256, 0, stream>>>(rA, rD, rW, counts);
  int nb = (n_total + 1023) / 1024;
  scan_block_k<<<nb, 1024, 0, stream>>>(counts, n_total, off_bb, parts);
  scan_block_k<<<1, 1024, 0, stream>>>(parts, nb, parts, nullptr);
  add_off_k<<<(n_total + 1 + 1023) / 1024, 1024, 0, stream>>>(off_bb, n_total, parts, E_TOTAL);
  part_scatter_all_k<<<nblk_total, 256, 0, stream>>>(rA, rD, rW, off_bb, pairs);
  fine_sort_all_k<<<nbuk_total, 1024, 0, stream>>>(rA, rD, rW, off_bb, pairs, csr_all);

  // ---- bf16 casts ----
  cast_all_k<<<2048, 256, 0, stream>>>(x_person, xpbf, N_PERSON * H / 4, x_movie, xmbf,
                                       N_MOVIE * H / 4);

  // 32 dsts per block (4 waves x 8 dsts)
  const int nbA = (N_MOVIE + 31) / 32, nbD = (N_MOVIE + 31) / 32, nbW = (N_PERSON + 31) / 32;
  const int gmM = (N_MOVIE + 255) / 256, gmP = (N_PERSON + 255) / 256;

  // ---- layer 1 pulls: acted, directed, www from xpbf ----
  {
    PullT pA = {xpbf, off_a, meanAbf, N_MOVIE, 0};
    PullT pD = {xpbf, off_d, meanDbf, N_MOVIE, nbA};
    PullT pW = {xpbf, off_w, meanWbf, N_PERSON, nbA + nbD};
    pull_all_k<<<nbA + nbD + nbW, 256, 0, stream>>>(pA, pD, pW, csr_all);
  }
  // ---- layer 1 GEMMs: movie (3 srcs) + person (2 srcs), one launch ----
  {
    GemmT gM = {meanAbf, meanDbf, xmbf,
                Wl_acted, Wl_directed, Wr_acted, Wr_directed, bl_acted, bl_directed,
                xm0bf, nullptr, nullptr, nullptr, N_MOVIE, 3, 0};
    GemmT gP = {meanWbf, xpbf, nullptr,
                Wl_www, Wr_www, nullptr, nullptr, bl_www, nullptr,
                xp0bf, nullptr, nullptr, nullptr, N_PERSON, 2, gmM};
    gemm_all_k<<<gmM + gmP, 256, 0, stream>>>(gM, gP);
  }
  // ---- layer 2 pulls: acted, directed from xp0bf ----
  {
    PullT pA = {xp0bf, off_a, meanAbf, N_MOVIE, 0};
    PullT pD = {xp0bf, off_d, meanDbf, N_MOVIE, nbA};
    PullT pZ = {nullptr, nullptr, nullptr, 0, 0};
    pull_all_k<<<nbA + nbD, 256, 0, stream>>>(pA, pD, pZ, csr_all);
  }
  // ---- layer 2 movie GEMM with fused final projection ----
  {
    GemmT gM = {meanAbf, meanDbf, xm0bf,
                Wl_acted + 4096, Wl_directed + 4096, Wr_acted + 4096, Wr_directed + 4096,
                bl_acted + 64, bl_directed + 64,
                nullptr, lin_W, lin_b, out, N_MOVIE, 3, 0};
    GemmT gZ = {nullptr, nullptr, nullptr, nullptr, nullptr, nullptr, nullptr, nullptr, nullptr,
                nullptr, nullptr, nullptr, nullptr, 0, 0, 0};
    gemm_all_k<<<gmM, 256, 0, stream>>>(gM, gZ);
  }
}